// Round 11
// baseline (192.523 us; speedup 1.0000x reference)
//
#include <hip/hip_runtime.h>
#include <math.h>

#define BB 4
#define CC 256
#define HWN 4096
#define NTOK 16384                 // BB*HWN
#define SCQ 0.09016844136f         // (1/sqrt(256)) * log2(e)

typedef __attribute__((ext_vector_type(8))) short short8;
typedef __attribute__((ext_vector_type(4))) float f32x4;
typedef unsigned short ushort_t;

__device__ __forceinline__ ushort_t f2bf(float f) {
    unsigned int u = __float_as_uint(f);
    unsigned int r = (u + 0x7FFFu + ((u >> 16) & 1u)) >> 16;   // RNE
    return (ushort_t)r;
}
__device__ __forceinline__ unsigned int pack2(float a, float b) {
    return (unsigned int)f2bf(a) | ((unsigned int)f2bf(b) << 16);
}
__device__ __forceinline__ float bf2f(ushort_t u) {
    return __uint_as_float(((unsigned int)u) << 16);
}

// ---------------------------------------------------------------------------
// prep v2: P[b_][a] = SCQ * sum_c W_k[c][b_] * W_q[c][a]   (bf16)
//          w1[b_]   = SCQ * sum_c W_k[c][b_] * b_q[c]
// Grid 1024: one 8x8 P-tile per block, one 64-c group per wave, LDS reduce.
// Also zeroes den/nx/ny.
// ---------------------------------------------------------------------------
__global__ __launch_bounds__(256) void prep_kernel(
    const float* __restrict__ q_w, const float* __restrict__ k_w,
    const float* __restrict__ q_bias,
    ushort_t* __restrict__ P, float* __restrict__ w1, float* __restrict__ zbuf)
{
    int bid = blockIdx.x, t = threadIdx.x;
    int gid = bid * 256 + t;
    if (gid < 3 * NTOK) zbuf[gid] = 0.f;

    int ta = bid & 31, tb = bid >> 5;
    int a_ = ta * 8 + (t & 7);
    int b_ = tb * 8 + ((t >> 3) & 7);
    int cg = t >> 6;                      // wave index = c-group

    float acc0 = 0.f, acc1 = 0.f;
    int c0 = cg * 64;
    #pragma unroll 8
    for (int c = c0; c < c0 + 64; c += 2) {
        acc0 = fmaf(k_w[(c + 0) * CC + b_], q_w[(c + 0) * CC + a_], acc0);
        acc1 = fmaf(k_w[(c + 1) * CC + b_], q_w[(c + 1) * CC + a_], acc1);
    }

    __shared__ float part[4][64];
    part[cg][t & 63] = acc0 + acc1;
    __syncthreads();
    if (t < 64) {
        float s = part[0][t] + part[1][t] + part[2][t] + part[3][t];
        int aa = ta * 8 + (t & 7), bb = tb * 8 + (t >> 3);
        P[bb * CC + aa] = f2bf(s * SCQ);
    }

    if (ta == 0 && t < 64) {
        int bb = tb * 8 + (t >> 3);
        int cs = (t & 7) * 32;
        float p = 0.f;
        #pragma unroll 8
        for (int cc = 0; cc < 32; cc++)
            p = fmaf(k_w[(cs + cc) * CC + bb], q_bias[cs + cc], p);
        p += __shfl_down(p, 4, 8);
        p += __shfl_down(p, 2, 8);
        p += __shfl_down(p, 1, 8);
        if ((t & 7) == 0) w1[bb] = p * SCQ;
    }
}

// ---------------------------------------------------------------------------
// tproj v2. Block = 32 tokens, grid 512. Double-buffered fp32 staging (loads
// for chunk k+1 in flight during transpose of chunk k). Streams raw bf16
// tokens to ft (B-side of scores), tv_j = w1 . f_j, then barrier-free
// f~ = P f MFMA (A = P rows, L2-hot, register-prefetched).
// ---------------------------------------------------------------------------
__global__ __launch_bounds__(256, 2) void tproj_kernel(
    const float* __restrict__ feature,
    const ushort_t* __restrict__ P, const float* __restrict__ w1,
    ushort_t* __restrict__ fq, ushort_t* __restrict__ ft,
    float* __restrict__ tv)
{
    int tt = blockIdx.x & 127;
    int b  = blockIdx.x >> 7;
    int tok0 = tt * 32;

    int t = threadIdx.x, w = t >> 6, lane = t & 63;
    int n16 = lane & 15, quad = lane >> 4;

    __shared__ float    lsA[2][64][34];   // [buf][c-in-chunk][tok] fp32
    __shared__ ushort_t lsB[32][264];     // [tok][c 0..255] bf16

    const float* F = feature + (size_t)(b * CC) * HWN;

    int cl = t >> 2, tg = (t & 3) * 8;      // stage: 64 rows x 32 tok
    int tokw = t >> 3, c8 = (t & 7) * 8;    // transpose: 32 tok x 8c-groups

    // preload chunk 0
    {
        const float* src = F + (size_t)cl * HWN + tok0 + tg;
        float4 v0 = *(const float4*)src;
        float4 v1 = *(const float4*)(src + 4);
        *(float2*)&lsA[0][cl][tg]     = make_float2(v0.x, v0.y);
        *(float2*)&lsA[0][cl][tg + 2] = make_float2(v0.z, v0.w);
        *(float2*)&lsA[0][cl][tg + 4] = make_float2(v1.x, v1.y);
        *(float2*)&lsA[0][cl][tg + 6] = make_float2(v1.z, v1.w);
    }
    __syncthreads();

    for (int ch = 0; ch < 4; ch++) {
        int cur = ch & 1;
        float4 v0, v1;
        if (ch + 1 < 4) {
            const float* src = F + (size_t)((ch + 1) * 64 + cl) * HWN + tok0 + tg;
            v0 = *(const float4*)src;
            v1 = *(const float4*)(src + 4);
        }
        // transpose current chunk (overlaps with the loads above in flight)
        uint4 o;
        o.x = pack2(lsA[cur][c8 + 0][tokw], lsA[cur][c8 + 1][tokw]);
        o.y = pack2(lsA[cur][c8 + 2][tokw], lsA[cur][c8 + 3][tokw]);
        o.z = pack2(lsA[cur][c8 + 4][tokw], lsA[cur][c8 + 5][tokw]);
        o.w = pack2(lsA[cur][c8 + 6][tokw], lsA[cur][c8 + 7][tokw]);
        *(uint4*)&lsB[tokw][ch * 64 + c8] = o;
        *(uint4*)&ft[(size_t)(b * HWN + tok0 + tokw) * CC + ch * 64 + c8] = o;
        if (ch + 1 < 4) {
            int nxt = cur ^ 1;
            *(float2*)&lsA[nxt][cl][tg]     = make_float2(v0.x, v0.y);
            *(float2*)&lsA[nxt][cl][tg + 2] = make_float2(v0.z, v0.w);
            *(float2*)&lsA[nxt][cl][tg + 4] = make_float2(v1.x, v1.y);
            *(float2*)&lsA[nxt][cl][tg + 6] = make_float2(v1.z, v1.w);
        }
        __syncthreads();
    }

    // per-key scalar: tv_j = w1 . f_j
    {
        int tok = t >> 3, cs = (t & 7) * 32;
        float tp = 0.f;
        #pragma unroll
        for (int cc = 0; cc < 32; cc++)
            tp = fmaf(bf2f(lsB[tok][cs + cc]), w1[cs + cc], tp);
        #pragma unroll
        for (int off = 4; off >= 1; off >>= 1)
            tp += __shfl_xor(tp, off, 8);
        if ((t & 7) == 0) tv[b * HWN + tok0 + tok] = tp;
    }

    int dw0 = w * 64;
    short8 ap[8], ap2[8];
    #pragma unroll
    for (int kc = 0; kc < 8; kc++)
        ap[kc] = *(const short8*)&P[(size_t)(dw0 + n16) * CC + kc * 32 + quad * 8];

    #pragma unroll
    for (int dsub = 0; dsub < 4; dsub++) {
        int d0 = dw0 + dsub * 16;
        if (dsub < 3) {
            #pragma unroll
            for (int kc = 0; kc < 8; kc++)
                ap2[kc] = *(const short8*)&P[(size_t)(d0 + 16 + n16) * CC + kc * 32 + quad * 8];
        }
        f32x4 acc[2];
        acc[0] = (f32x4){0.f, 0.f, 0.f, 0.f};
        acc[1] = (f32x4){0.f, 0.f, 0.f, 0.f};
        #pragma unroll
        for (int kc = 0; kc < 8; kc++) {
            #pragma unroll
            for (int tokt = 0; tokt < 2; tokt++) {
                short8 bf = *(const short8*)&lsB[tokt * 16 + n16][kc * 32 + quad * 8];
                acc[tokt] = __builtin_amdgcn_mfma_f32_16x16x32_bf16(ap[kc], bf, acc[tokt], 0, 0, 0);
            }
        }
        #pragma unroll
        for (int tokt = 0; tokt < 2; tokt++) {
            size_t row = (size_t)(b * HWN + tok0 + tokt * 16 + n16) * CC + d0 + quad * 4;
            ushort4 oq;
            oq.x = f2bf(acc[tokt][0]); oq.y = f2bf(acc[tokt][1]);
            oq.z = f2bf(acc[tokt][2]); oq.w = f2bf(acc[tokt][3]);
            *(ushort4*)&fq[row] = oq;
        }
        #pragma unroll
        for (int kc = 0; kc < 8; kc++) ap[kc] = ap2[kc];
    }
}

// ---------------------------------------------------------------------------
// Flash MFMA attention: R7 structure with 64-key stages (8 barriers/block).
// Block = (b, 256-q, 512-key range), 4 waves x 64 q-rows; grid 512 qt-fastest.
// Double-buffered 2 x 32 KB XOR-swizzled LDS K-tiles; stage k+1 issued right
// after the barrier -> drains a full 128-MFMA compute phase later.
// p = exp2(f~_i . f_j) * etv_j with etv/evx/evy precomputed per key.
// No-max softmax => key-split additively exact via atomics.
// ---------------------------------------------------------------------------
__global__ __launch_bounds__(256, 2) void attn_kernel(
    const ushort_t* __restrict__ fq, const ushort_t* __restrict__ ft,
    const float* __restrict__ flow, const float* __restrict__ tv,
    float* __restrict__ den_g, float* __restrict__ nx_g, float* __restrict__ ny_g)
{
    int id = blockIdx.x;
    int qt = id & 15; id >>= 4;
    int sr = id & 7;  id >>= 3;
    int b = id;

    int t = threadIdx.x;
    int w = t >> 6, lane = t & 63;
    int n16 = lane & 15, quad = lane >> 4;

    int q0 = qt * 256 + w * 64;
    int s_beg = sr * 512;

    const ushort_t* Qb = fq + (size_t)b * HWN * CC;
    const ushort_t* Kb = ft + (size_t)b * HWN * CC;

    __shared__ __align__(16) ushort_t lk[2][16384];  // 2 x 32 KB swizzled K
    __shared__ float lflow[1536];                    // 512 evx + 512 evy + 512 etv

    const float* fx = flow + (size_t)b * 2 * HWN;
    const float* fy = fx + HWN;
    #pragma unroll
    for (int j = 0; j < 2; j++) {
        int sidx = t + j * 256;
        float etv = exp2f(tv[b * HWN + s_beg + sidx]);
        lflow[sidx]        = etv * fx[s_beg + sidx];
        lflow[sidx + 512]  = etv * fy[s_beg + sidx];
        lflow[sidx + 1024] = etv;
    }

    short8 qf[4][8];
    #pragma unroll
    for (int tq = 0; tq < 4; tq++)
        #pragma unroll
        for (int c = 0; c < 8; c++)
            qf[tq][c] = *(const short8*)&Qb[(size_t)(q0 + tq * 16 + n16) * CC
                                            + c * 32 + quad * 8];

    // staging source offsets (XOR swizzle on 16B granules), loop-invariant
    int srcoff[8];
    #pragma unroll
    for (int i = 0; i < 8; i++) {
        int G = i * 256 + t;
        int r = G >> 5, j = G & 31;        // 64 rows x 32 granules
        srcoff[i] = (r * 32 + (j ^ (r & 31))) * 16;
    }
    int p16[8];
    #pragma unroll
    for (int c = 0; c < 8; c++)
        p16[c] = (((c * 4 + quad) ^ n16) & 31) * 16;

    float den[4][4], nxa[4][4], nya[4][4];
    #pragma unroll
    for (int tq = 0; tq < 4; tq++)
        #pragma unroll
        for (int r = 0; r < 4; r++) { den[tq][r] = 0.f; nxa[tq][r] = 0.f; nya[tq][r] = 0.f; }

    // prologue: stage 64-key tile 0 into buffer 0
    {
        const char* gsrc = (const char*)(Kb + (size_t)s_beg * CC);
        char* ldst = (char*)lk[0] + t * 16;
        #pragma unroll
        for (int i = 0; i < 8; i++)
            __builtin_amdgcn_global_load_lds(
                (const __attribute__((address_space(1))) unsigned int*)(gsrc + srcoff[i]),
                (__attribute__((address_space(3))) unsigned int*)(ldst + i * 4096),
                16, 0, 0);
    }

    for (int st = 0; st < 8; st++) {
        __syncthreads();   // buffer st&1 staged; prior reads of other buffer done
        if (st + 1 < 8) {
            const char* gsrc = (const char*)(Kb + (size_t)(s_beg + (st + 1) * 64) * CC);
            char* ldst = (char*)lk[(st + 1) & 1] + t * 16;
            #pragma unroll
            for (int i = 0; i < 8; i++)
                __builtin_amdgcn_global_load_lds(
                    (const __attribute__((address_space(1))) unsigned int*)(gsrc + srcoff[i]),
                    (__attribute__((address_space(3))) unsigned int*)(ldst + i * 4096),
                    16, 0, 0);
        }
        const char* base = (const char*)lk[st & 1];

        #pragma unroll
        for (int bt = 0; bt < 4; bt++) {
            int rbase = (bt * 16 + n16) * 512;
            int x16   = (bt & 1) ? 256 : 0;
            f32x4 a0 = {0.f, 0.f, 0.f, 0.f};
            f32x4 a1 = {0.f, 0.f, 0.f, 0.f};
            f32x4 a2 = {0.f, 0.f, 0.f, 0.f};
            f32x4 a3 = {0.f, 0.f, 0.f, 0.f};
            #pragma unroll
            for (int c = 0; c < 8; c++) {
                short8 kf = *(const short8*)(base + rbase + (p16[c] ^ x16));
                a0 = __builtin_amdgcn_mfma_f32_16x16x32_bf16(qf[0][c], kf, a0, 0, 0, 0);
                a1 = __builtin_amdgcn_mfma_f32_16x16x32_bf16(qf[1][c], kf, a1, 0, 0, 0);
                a2 = __builtin_amdgcn_mfma_f32_16x16x32_bf16(qf[2][c], kf, a2, 0, 0, 0);
                a3 = __builtin_amdgcn_mfma_f32_16x16x32_bf16(qf[3][c], kf, a3, 0, 0, 0);
            }
            int sidx = st * 64 + bt * 16 + n16;
            float evx = lflow[sidx];
            float evy = lflow[512 + sidx];
            float etv = lflow[1024 + sidx];
            #pragma unroll
            for (int r = 0; r < 4; r++) {
                float p0 = exp2f(a0[r]);
                float p1 = exp2f(a1[r]);
                float p2 = exp2f(a2[r]);
                float p3 = exp2f(a3[r]);
                den[0][r] = fmaf(p0, etv, den[0][r]); den[1][r] = fmaf(p1, etv, den[1][r]);
                den[2][r] = fmaf(p2, etv, den[2][r]); den[3][r] = fmaf(p3, etv, den[3][r]);
                nxa[0][r] = fmaf(p0, evx, nxa[0][r]); nxa[1][r] = fmaf(p1, evx, nxa[1][r]);
                nxa[2][r] = fmaf(p2, evx, nxa[2][r]); nxa[3][r] = fmaf(p3, evx, nxa[3][r]);
                nya[0][r] = fmaf(p0, evy, nya[0][r]); nya[1][r] = fmaf(p1, evy, nya[1][r]);
                nya[2][r] = fmaf(p2, evy, nya[2][r]); nya[3][r] = fmaf(p3, evy, nya[3][r]);
            }
        }
    }

    #pragma unroll
    for (int tq = 0; tq < 4; tq++)
        #pragma unroll
        for (int r = 0; r < 4; r++) {
            #pragma unroll
            for (int off = 8; off >= 1; off >>= 1) {
                den[tq][r] += __shfl_down(den[tq][r], off, 16);
                nxa[tq][r] += __shfl_down(nxa[tq][r], off, 16);
                nya[tq][r] += __shfl_down(nya[tq][r], off, 16);
            }
        }
    if (n16 == 0) {
        #pragma unroll
        for (int tq = 0; tq < 4; tq++)
            #pragma unroll
            for (int r = 0; r < 4; r++) {
                int qrow = q0 + tq * 16 + quad * 4 + r;
                int gi = b * HWN + qrow;
                atomicAdd(&den_g[gi], den[tq][r]);
                atomicAdd(&nx_g[gi],  nxa[tq][r]);
                atomicAdd(&ny_g[gi],  nya[tq][r]);
            }
    }
}

// ---------------------------------------------------------------------------
__global__ __launch_bounds__(256) void finalize_kernel(
    const float* __restrict__ den_g, const float* __restrict__ nx_g,
    const float* __restrict__ ny_g, float* __restrict__ out)
{
    int idx = blockIdx.x * 256 + threadIdx.x;  // b*HW + n
    int b = idx >> 12, n = idx & 4095;
    float inv = 1.0f / den_g[idx];
    out[(size_t)b * 2 * HWN + n]       = nx_g[idx] * inv;
    out[(size_t)b * 2 * HWN + HWN + n] = ny_g[idx] * inv;
}

extern "C" void kernel_launch(void* const* d_in, const int* in_sizes, int n_in,
                              void* d_out, int out_size, void* d_ws, size_t ws_size,
                              hipStream_t stream) {
    const float* feature = (const float*)d_in[0];
    const float* flow    = (const float*)d_in[1];
    const float* q_w     = (const float*)d_in[2];
    const float* q_b     = (const float*)d_in[3];
    const float* k_w     = (const float*)d_in[4];
    // k_b unused: b_k-side softmax terms are per-row constants and cancel
    float* out = (float*)d_out;

    ushort_t* fq = (ushort_t*)d_ws;                       // [NTOK][CC] bf16
    ushort_t* ft = fq + (size_t)NTOK * CC;                // [NTOK][CC] bf16
    ushort_t* P  = ft + (size_t)NTOK * CC;                // [CC][CC] bf16
    float* w1  = (float*)(P + (size_t)CC * CC);           // [CC]
    float* tvb = w1 + CC;                                 // [NTOK]
    float* den = tvb + NTOK;                              // [NTOK]
    float* nx  = den + NTOK;
    float* ny  = nx + NTOK;

    prep_kernel<<<1024, 256, 0, stream>>>(q_w, k_w, q_b, P, w1, den);  // + zeroing
    tproj_kernel<<<512, 256, 0, stream>>>(feature, P, w1, fq, ft, tvb);
    attn_kernel<<<512, 256, 0, stream>>>(fq, ft, flow, tvb, den, nx, ny);
    finalize_kernel<<<64, 256, 0, stream>>>(den, nx, ny, out);
}